// Round 7
// baseline (2870.648 us; speedup 1.0000x reference)
//
#include <hip/hip_runtime.h>

typedef unsigned short u16;
typedef __attribute__((ext_vector_type(8))) __bf16 bf16x8;
typedef __attribute__((ext_vector_type(4))) float f32x4;
typedef __attribute__((ext_vector_type(4))) unsigned int u32x4;
typedef __attribute__((ext_vector_type(2))) unsigned int u32x2;

// ---------- workspace layout (bytes) ----------
#define GX_OFF   0ull                      // gates_x [32768][1024][4] bf16 = 268435456
#define FT_OFF   268435456ull              // ft      [32768][1024]    bf16 = 67108864
#define WT_OFF   335544320ull              // Wt      [4096][2048]     bf16 = 16777216
#define W1T_OFF  352321536ull              // W1t     [2048][256]      bf16 = 1048576 (dead after k_field)
#define CB_OFF   352321536ull              // cbuf [64][1024] f32 = 262144 (overlays W1t; coop: tagged-h lo half)
#define HF_OFF   352583680ull              // hfin [64][1024] f32 = 262144 (coop: tagged-h hi half)
#define HB_OFF   353370112ull              // hbuf [2][64][1024] bf16 = 262144 (fallback path only)
#define WS_NEED  (HB_OFF + 262144ull)      // = 353632256
// coop path: tagged h buffer hb32[2][64][1024] u32 = 524288 B at CB_OFF
// (cbuf+hfin are contiguous and zeroed by k_zero; coop path never uses them as f32)

#define NBLK 256

__device__ __forceinline__ float b2f(u16 u) {
    unsigned x = ((unsigned)u) << 16;
    return __builtin_bit_cast(float, x);
}
__device__ __forceinline__ u16 f2b(float f) {   // rne f32->bf16
    unsigned u = __builtin_bit_cast(unsigned, f);
    unsigned r = (u + 0x7FFFu + ((u >> 16) & 1u)) >> 16;
    return (u16)r;
}
__device__ __forceinline__ float fsigm(float x) {
    return __builtin_amdgcn_rcpf(1.f + __expf(-x));
}
__device__ __forceinline__ float ftanh2(float x) {
    return 2.f * __builtin_amdgcn_rcpf(1.f + __expf(-2.f * x)) - 1.f;
}
__device__ __forceinline__ bf16x8 ld_frag(const u16* p) {
    u32x4 v = *(const u32x4*)p;
    return __builtin_bit_cast(bf16x8, v);
}
__device__ __forceinline__ f32x4 mfma16(bf16x8 a, bf16x8 b, f32x4 c) {
    return __builtin_amdgcn_mfma_f32_16x16x32_bf16(a, b, c, 0, 0, 0);
}
// load 8 f32, convert to 8 bf16 packed in u32x4
__device__ __forceinline__ u32x4 cvt8(const float* p) {
    f32x4 a = *(const f32x4*)p;
    f32x4 b = *(const f32x4*)(p + 4);
    u32x4 r;
    r.x = (unsigned)f2b(a[0]) | ((unsigned)f2b(a[1]) << 16);
    r.y = (unsigned)f2b(a[2]) | ((unsigned)f2b(a[3]) << 16);
    r.z = (unsigned)f2b(b[0]) | ((unsigned)f2b(b[1]) << 16);
    r.w = (unsigned)f2b(b[2]) | ((unsigned)f2b(b[3]) << 16);
    return r;
}

// ALL cross-block communication at system scope (sc0 sc1): L1+L2 bypass, the
// memory-side Infinity Cache is the coherence point. Proven replay-safe (r2/r3/r6).
// L2-scope (sc0-only) was tried in r5 and is NOT replay-safe — do not reintroduce.
__device__ __forceinline__ u32x4 ld16u_coh(const unsigned* p) {
    u32x4 v;
    asm volatile("global_load_dwordx4 %0, %1, off sc0 sc1" : "=v"(v) : "v"(p));
    return v;
}
__device__ __forceinline__ void st4_coh(unsigned* p, unsigned v) {
    asm volatile("global_store_dword %0, %1, off sc0 sc1" :: "v"(p), "v"(v) : "memory");
}

// ---------- transpose+cast: out_bf16[c][r] = f2b(in_f32[r][c]) ----------
__global__ void k_transpose(const float* __restrict__ in, u16* __restrict__ out, int R, int C) {
    __shared__ u16 tl[64][65];
    int tx = threadIdx.x, ty = threadIdx.y;
    int c0 = blockIdx.x * 64, r0 = blockIdx.y * 64;
#pragma unroll
    for (int i = 0; i < 16; i++) {
        int a = ty + i * 4;
        tl[a][tx] = f2b(in[(size_t)(r0 + a) * C + c0 + tx]);
    }
    __syncthreads();
#pragma unroll
    for (int i = 0; i < 16; i++) {
        int a = ty + i * 4;
        out[(size_t)(c0 + a) * R + r0 + tx] = tl[tx][a];
    }
}

// ---------- field GEMM: ft = sigmoid(F@W1[:, :1024]+b) * tanh(F@W1[:, 1024:]+b) ----------
// Rows (bb, t) with t >= len[bb] are dead downstream — skip tiles entirely past len.
__global__ __launch_bounds__(256) void k_field(const float* __restrict__ F, const u16* __restrict__ W1t,
                                               const float* __restrict__ bW1, const int* __restrict__ len,
                                               u16* __restrict__ ftw) {
    int m0 = blockIdx.y * 128;
    if ((m0 & 511) >= len[m0 >> 9]) return;   // whole tile beyond this row's length
    int n0 = blockIdx.x * 64;
    __shared__ u16 As[128 * 40];
    __shared__ u16 Bs[128 * 40];
    int tid = threadIdx.x, w = tid >> 6, lane = tid & 63, quad = lane >> 4, l16 = lane & 15;
    f32x4 acc[2][8];
#pragma unroll
    for (int mt = 0; mt < 2; mt++)
#pragma unroll
        for (int nt = 0; nt < 8; nt++) acc[mt][nt] = (f32x4){0.f, 0.f, 0.f, 0.f};

    for (int kc = 0; kc < 8; kc++) {
        __syncthreads();
#pragma unroll
        for (int it = 0; it < 2; it++) {
            int q = tid + it * 256, row = q >> 2, sub = q & 3;
            u32x4 va = cvt8(F + (size_t)(m0 + row) * 256 + kc * 32 + sub * 8);
            *(u32x4*)(As + row * 40 + sub * 8) = va;
            int brow = (row < 64) ? (n0 + row) : (1024 + n0 + row - 64);
            u32x4 vb = *(const u32x4*)(W1t + (size_t)brow * 256 + kc * 32 + sub * 8);
            *(u32x4*)(Bs + row * 40 + sub * 8) = vb;
        }
        __syncthreads();
        bf16x8 af[2], bfr[8];
#pragma unroll
        for (int mt = 0; mt < 2; mt++) af[mt] = ld_frag(As + (w * 32 + mt * 16 + l16) * 40 + quad * 8);
#pragma unroll
        for (int nt = 0; nt < 8; nt++) bfr[nt] = ld_frag(Bs + (nt * 16 + l16) * 40 + quad * 8);
#pragma unroll
        for (int mt = 0; mt < 2; mt++)
#pragma unroll
            for (int nt = 0; nt < 8; nt++) acc[mt][nt] = mfma16(af[mt], bfr[nt], acc[mt][nt]);
    }
#pragma unroll
    for (int nth = 0; nth < 4; nth++) {
        float br = bW1[n0 + nth * 16 + l16];
        float bd = bW1[1024 + n0 + nth * 16 + l16];
#pragma unroll
        for (int mt = 0; mt < 2; mt++) {
#pragma unroll
            for (int j = 0; j < 4; j++) {
                int r = m0 + w * 32 + mt * 16 + quad * 4 + j;
                float rv = acc[mt][nth][j] + br;
                float dv = acc[mt][nth + 4][j] + bd;
                ftw[(size_t)r * 1024 + n0 + nth * 16 + l16] = f2b(fsigm(rv) * ftanh2(dv));
            }
        }
    }
}

// ---------- x GEMM: gx[r][H][g] = X@W[:1024,:] + bW (gate-interleaved, bf16 store) ----------
__global__ __launch_bounds__(256) void k_xgemm(const float* __restrict__ X, const u16* __restrict__ Wt,
                                               const float* __restrict__ bWv, const int* __restrict__ len,
                                               u16* __restrict__ gx) {
    int m0 = blockIdx.y * 128;
    if ((m0 & 511) >= len[m0 >> 9]) return;   // whole tile beyond this row's length
    int n0 = blockIdx.x * 128;
    __shared__ u16 As[128 * 40];
    __shared__ u16 Bs[128 * 40];
    int tid = threadIdx.x, w = tid >> 6, lane = tid & 63, quad = lane >> 4, l16 = lane & 15;
    int mq = (w & 1) * 64, nq = (w >> 1) * 64;
    f32x4 acc[4][4];
#pragma unroll
    for (int mt = 0; mt < 4; mt++)
#pragma unroll
        for (int nt = 0; nt < 4; nt++) acc[mt][nt] = (f32x4){0.f, 0.f, 0.f, 0.f};

    for (int kc = 0; kc < 32; kc++) {
        __syncthreads();
#pragma unroll
        for (int it = 0; it < 2; it++) {
            int q = tid + it * 256, row = q >> 2, sub = q & 3;
            u32x4 va = cvt8(X + (size_t)(m0 + row) * 1024 + kc * 32 + sub * 8);
            *(u32x4*)(As + row * 40 + sub * 8) = va;
            u32x4 vb = *(const u32x4*)(Wt + (size_t)(n0 + row) * 2048 + kc * 32 + sub * 8);
            *(u32x4*)(Bs + row * 40 + sub * 8) = vb;
        }
        __syncthreads();
        bf16x8 af[4], bfr[4];
#pragma unroll
        for (int mt = 0; mt < 4; mt++) af[mt] = ld_frag(As + (mq + mt * 16 + l16) * 40 + quad * 8);
#pragma unroll
        for (int nt = 0; nt < 4; nt++) bfr[nt] = ld_frag(Bs + (nq + nt * 16 + l16) * 40 + quad * 8);
#pragma unroll
        for (int mt = 0; mt < 4; mt++)
#pragma unroll
            for (int nt = 0; nt < 4; nt++) acc[mt][nt] = mfma16(af[mt], bfr[nt], acc[mt][nt]);
    }
#pragma unroll
    for (int nt = 0; nt < 4; nt++) {
        int gcol = n0 + nq + nt * 16 + l16;
        int hcol = gcol & 1023, g = gcol >> 10;
        float bw = bWv[gcol];
#pragma unroll
        for (int mt = 0; mt < 4; mt++) {
#pragma unroll
            for (int j = 0; j < 4; j++) {
                int r = m0 + mq + mt * 16 + quad * 4 + j;
                gx[(size_t)r * 4096 + hcol * 4 + g] = f2b(acc[mt][nt][j] + bw);
            }
        }
    }
}

// ---------- zero-init recurrent state ----------
// Zeroes: fallback hbuf (u16) + cbuf/hfin region = the coop tagged-h buffer
// (tag 0 == generation of step 0 -> step-0 polls pass immediately).
__global__ void k_zero(u16* __restrict__ hbuf, float* __restrict__ cbuf, float* __restrict__ hfin) {
    int idx = blockIdx.x * 1024 + threadIdx.x;  // 64k threads
    hbuf[idx] = 0; hbuf[65536 + idx] = 0;
    cbuf[idx] = 0.f; hfin[idx] = 0.f;
}

// ---------- persistent cooperative LSTM: all 512 steps in one kernel ----------
// grid = 256 blocks = 4 bbg (16-row batch slices) x 64 wg (16 H-cols).
// h exchange: TAGGED dwords u32 = (gen<<16)|bf16(h), double-buffered by parity.
// Producers fire one tagged store per thread (no drain, no flag, no barrier);
// consumers poll by loading their actual MFMA A-operands and min-reducing the
// tag halves — detection and data fetch are the SAME L3 round-trip.
// Overwrite safety: every block consumes all 64 slots of its group, so writing
// tag t+2 (same parity as t) implies all blocks finished reading tag t.
// LDS red[] double-buffered by parity -> single raw s_barrier per step, no
// vmcnt drain anywhere outside the poll.
__global__ __launch_bounds__(256, 1) void k_lstm(const u16* __restrict__ Wt, const u16* __restrict__ gx,
                                                 const u16* __restrict__ ftw, const int* __restrict__ len,
                                                 float* __restrict__ out, unsigned* __restrict__ hb32) {
    __shared__ __align__(16) float red[2][4 * 64 * 20];
    int tid = threadIdx.x;
    int w = tid >> 6, lane = tid & 63, quad = lane >> 4, l16 = lane & 15;
    int blk = blockIdx.x;
    int bbg = blk & 3, wg = blk >> 2;

    // ---- one-time: weights into registers. wave w owns K range [w*256, w*256+256) ----
    bf16x8 breg[8][4];
#pragma unroll
    for (int kk = 0; kk < 8; kk++)
#pragma unroll
        for (int nt = 0; nt < 4; nt++) {
            size_t gcol = (size_t)nt * 1024 + wg * 16 + l16;   // gate nt, hcol wg*16+l16
            breg[kk][nt] = ld_frag(Wt + gcol * 2048 + 1024 + w * 256 + kk * 32 + quad * 8);
        }

    // per-thread epilogue ownership: one (bb, Hcol) pair
    int bbl = tid >> 4, hc = tid & 15;
    int bb = bbg * 16 + bbl;
    int Hcol = wg * 16 + hc;
    int mylen = len[bb];
    float hreg = 0.f, creg = 0.f;

    // A-read base: row bbg*16+l16, col block w*256 + quad*8 (u32 elements)
    const unsigned* ab0 = hb32 + (size_t)(bbg * 16 + l16) * 1024 + w * 256 + quad * 8;
    unsigned* hst0 = hb32 + (size_t)bb * 1024 + Hcol;

    // prefetch t=0 epilogue operands
    u32x2 gq = *(const u32x2*)(gx + ((size_t)bb * 512) * 4096 + (size_t)Hcol * 4);
    float ftv = b2f(ftw[((size_t)bb * 512) * 1024 + Hcol]);

    for (int t = 0; t < 512; t++) {
        const unsigned* ab = ab0 + (size_t)(t & 1) * 65536;
        unsigned gen = (unsigned)t;

        // ---- fused poll+fetch: load A-operands, accept when min tag >= t ----
        u32x4 av[16];
        for (;;) {
#pragma unroll
            for (int kk = 0; kk < 8; kk++) {
                av[2 * kk]     = ld16u_coh(ab + kk * 32);
                av[2 * kk + 1] = ld16u_coh(ab + kk * 32 + 4);
            }
            asm volatile("s_waitcnt vmcnt(0)" ::: "memory");
            unsigned mn = 0xFFFFFFFFu;
#pragma unroll
            for (int j = 0; j < 16; j++) {
                unsigned a = av[j].x < av[j].y ? av[j].x : av[j].y;
                unsigned b = av[j].z < av[j].w ? av[j].z : av[j].w;
                a = a < b ? a : b;
                mn = mn < a ? mn : a;
            }
            if (__all((int)((mn >> 16) >= gen))) break;
            __builtin_amdgcn_s_sleep(1);
        }
        __builtin_amdgcn_sched_barrier(0);   // keep MFMAs below the accepted loads (rule #18)

        // ---- strip tags, pack bf16 pairs, MFMA ----
        f32x4 acc[4];
#pragma unroll
        for (int nt = 0; nt < 4; nt++) acc[nt] = (f32x4){0.f, 0.f, 0.f, 0.f};
#pragma unroll
        for (int kk = 0; kk < 8; kk++) {
            u32x4 a = av[2 * kk], b = av[2 * kk + 1];
            u32x4 fr;
            fr.x = (a.x & 0xffffu) | (a.y << 16);
            fr.y = (a.z & 0xffffu) | (a.w << 16);
            fr.z = (b.x & 0xffffu) | (b.y << 16);
            fr.w = (b.z & 0xffffu) | (b.w << 16);
            bf16x8 af = __builtin_bit_cast(bf16x8, fr);
#pragma unroll
            for (int nt = 0; nt < 4; nt++) acc[nt] = mfma16(af, breg[kk][nt], acc[nt]);
        }
        float* rp = red[t & 1];
#pragma unroll
        for (int nt = 0; nt < 4; nt++)
            *(f32x4*)&rp[(w * 64 + nt * 16 + l16) * 20 + quad * 4] = acc[nt];
        // raw barrier: only LDS must be drained; out/h stores keep flying
        asm volatile("s_waitcnt lgkmcnt(0)" ::: "memory");
        __builtin_amdgcn_sched_barrier(0);
        __builtin_amdgcn_s_barrier();
        __builtin_amdgcn_sched_barrier(0);

        // cross-wave K-reduction (same order as fallback k_step: w = 0..3)
        float G[4];
#pragma unroll
        for (int g = 0; g < 4; g++) {
            int c = g * 16 + hc;
            G[g] = rp[(0 * 64 + c) * 20 + bbl] + rp[(1 * 64 + c) * 20 + bbl]
                 + rp[(2 * 64 + c) * 20 + bbl] + rp[(3 * 64 + c) * 20 + bbl];
        }
        float iv = G[0] + b2f((u16)(gq.x & 0xffff));
        float jv = G[1] + b2f((u16)(gq.x >> 16));
        float fv = G[2] + b2f((u16)(gq.y & 0xffff));
        float ov = G[3] + b2f((u16)(gq.y >> 16));
        float cn = fsigm(fv + 1.f) * creg + fsigm(iv) * ftanh2(jv) + ftv;
        float hn = fsigm(ov) * ftanh2(cn);
        bool act = t < mylen;
        hreg = act ? hn : hreg;
        creg = act ? cn : creg;
        // critical cross-block edge FIRST: tagged h, fire-and-forget
        st4_coh(hst0 + (size_t)((t + 1) & 1) * 65536,
                ((unsigned)(t + 1) << 16) | (unsigned)f2b(hreg));
        out[(size_t)bb * 524288 + (size_t)t * 1024 + Hcol] = act ? hn : 0.f;
        if (t != 511) {
            // next-step operands; latency hides under next poll
            size_t rowi = (size_t)bb * 512 + (t + 1);
            gq = *(const u32x2*)(gx + rowi * 4096 + (size_t)Hcol * 4);
            ftv = b2f(ftw[rowi * 1024 + Hcol]);
        }
    }
    // final states straight from registers
    out[33554432 + (size_t)bb * 1024 + Hcol] = hreg;
    out[33554432 + 65536 + (size_t)bb * 1024 + Hcol] = creg;
}

// ---------- fallback: one LSTM time-step (512 sequential launches) ----------
__global__ __launch_bounds__(256) void k_step(const u16* __restrict__ Wt, const u16* __restrict__ gx,
                                              const u16* __restrict__ ftw, const int* __restrict__ len,
                                              float* __restrict__ out, u16* __restrict__ hbuf,
                                              float* __restrict__ cbuf, float* __restrict__ hfin, int t) {
    int wg = blockIdx.x;
    int tid = threadIdx.x, w = tid >> 6, lane = tid & 63, quad = lane >> 4, l16 = lane & 15;
    __shared__ float red[4 * 64 * 68];  // [wave][c][row(+pad)]

    const u16* hb = hbuf + (t & 1) * 65536;
    u16* hbn = hbuf + ((t + 1) & 1) * 65536;

    f32x4 acc[4][4];
#pragma unroll
    for (int mt = 0; mt < 4; mt++)
#pragma unroll
        for (int nt = 0; nt < 4; nt++) acc[mt][nt] = (f32x4){0.f, 0.f, 0.f, 0.f};

#pragma unroll
    for (int kk = 0; kk < 8; kk++) {
        bf16x8 af[4], bq[4];
#pragma unroll
        for (int mt = 0; mt < 4; mt++)
            af[mt] = ld_frag(hb + (mt * 16 + l16) * 1024 + w * 256 + kk * 32 + quad * 8);
#pragma unroll
        for (int nt = 0; nt < 4; nt++) {
            int c = nt * 16 + l16;
            int gcol = (c & 3) * 1024 + wg * 16 + (c >> 2);
            bq[nt] = ld_frag(Wt + (size_t)gcol * 2048 + 1024 + w * 256 + kk * 32 + quad * 8);
        }
#pragma unroll
        for (int mt = 0; mt < 4; mt++)
#pragma unroll
            for (int nt = 0; nt < 4; nt++) acc[mt][nt] = mfma16(af[mt], bq[nt], acc[mt][nt]);
    }

#pragma unroll
    for (int mt = 0; mt < 4; mt++)
#pragma unroll
        for (int nt = 0; nt < 4; nt++)
            *(f32x4*)&red[(w * 64 + nt * 16 + l16) * 68 + mt * 16 + quad * 4] = acc[mt][nt];
    __syncthreads();

    int hc = tid & 15, rg = tid >> 4;
    int Hcol = wg * 16 + hc;
    f32x4 Gv[4];
#pragma unroll
    for (int g = 0; g < 4; g++) {
        int c = hc * 4 + g;
        f32x4 s = *(f32x4*)&red[(0 * 64 + c) * 68 + rg * 4];
#pragma unroll
        for (int wq = 1; wq < 4; wq++) s += *(f32x4*)&red[(wq * 64 + c) * 68 + rg * 4];
        Gv[g] = s;
    }

#pragma unroll
    for (int j = 0; j < 4; j++) {
        int bb = rg * 4 + j;
        size_t rowi = (size_t)bb * 512 + t;
        u32x2 gq = *(const u32x2*)(gx + rowi * 4096 + (size_t)Hcol * 4);
        float iv = Gv[0][j] + b2f((u16)(gq.x & 0xffff));
        float jv = Gv[1][j] + b2f((u16)(gq.x >> 16));
        float fv = Gv[2][j] + b2f((u16)(gq.y & 0xffff));
        float ov = Gv[3][j] + b2f((u16)(gq.y >> 16));
        float ftv = b2f(ftw[rowi * 1024 + Hcol]);
        float cprev = cbuf[bb * 1024 + Hcol];
        float hprev = hfin[bb * 1024 + Hcol];
        float cn = fsigm(fv + 1.f) * cprev + fsigm(iv) * ftanh2(jv) + ftv;
        float hn = fsigm(ov) * ftanh2(cn);
        bool act = t < len[bb];
        out[(size_t)bb * 524288 + (size_t)t * 1024 + Hcol] = act ? hn : 0.f;
        hbn[bb * 1024 + Hcol] = f2b(act ? hn : hprev);
        cbuf[bb * 1024 + Hcol] = act ? cn : cprev;
        hfin[bb * 1024 + Hcol] = act ? hn : hprev;
    }
}

// ---------- fallback final state writeout (f32) ----------
__global__ void k_fin(const float* __restrict__ hfin, const float* __restrict__ cbuf,
                      float* __restrict__ out) {
    int idx = blockIdx.x * 1024 + threadIdx.x;  // 65536
    out[33554432 + idx] = hfin[idx];
    out[33554432 + 65536 + idx] = cbuf[idx];
}

extern "C" void kernel_launch(void* const* d_in, const int* in_sizes, int n_in,
                              void* d_out, int out_size, void* d_ws, size_t ws_size,
                              hipStream_t stream) {
    (void)in_sizes; (void)n_in; (void)out_size;
    if (ws_size < WS_NEED) return;

    const float* X   = (const float*)d_in[0];
    const float* F   = (const float*)d_in[1];
    const int*   len = (const int*)d_in[2];
    const float* W   = (const float*)d_in[3];
    const float* bW  = (const float*)d_in[4];
    const float* W1  = (const float*)d_in[5];
    const float* bW1 = (const float*)d_in[6];
    float* out = (float*)d_out;

    char* ws = (char*)d_ws;
    u16*   gx   = (u16*)(ws + GX_OFF);
    u16*   ftw  = (u16*)(ws + FT_OFF);
    u16*   Wt   = (u16*)(ws + WT_OFF);
    u16*   W1t  = (u16*)(ws + W1T_OFF);
    float* cbuf = (float*)(ws + CB_OFF);   // fallback c-state; coop: tagged-h buffer lo half
    float* hfin = (float*)(ws + HF_OFF);   // fallback h-state; coop: tagged-h buffer hi half
    u16*   hbuf = (u16*)(ws + HB_OFF);     // fallback h exchange
    unsigned* hb32 = (unsigned*)(ws + CB_OFF);  // coop tagged h [2][64][1024] u32

    k_transpose<<<dim3(64, 32), dim3(64, 4), 0, stream>>>(W, Wt, 2048, 4096);
    k_transpose<<<dim3(32, 4), dim3(64, 4), 0, stream>>>(W1, W1t, 256, 2048);
    k_field<<<dim3(16, 256), 256, 0, stream>>>(F, W1t, bW1, len, ftw);
    k_xgemm<<<dim3(32, 256), 256, 0, stream>>>(X, Wt, bW, len, gx);
    k_zero<<<64, 1024, 0, stream>>>(hbuf, cbuf, hfin);   // zeroes hbuf + tagged-h region

    void* args[6] = {(void*)&Wt, (void*)&gx, (void*)&ftw, (void*)&len,
                     (void*)&out, (void*)&hb32};
    hipError_t e = hipLaunchCooperativeKernel((const void*)k_lstm, dim3(NBLK), dim3(256),
                                              args, 0, stream);
    if (e != hipSuccess) {
        // fallback: proven 512-launch path (cbuf/hfin still zeroed and unaliased here)
        for (int t = 0; t < 512; t++)
            k_step<<<64, 256, 0, stream>>>(Wt, gx, ftw, len, out, hbuf, cbuf, hfin, t);
        k_fin<<<64, 1024, 0, stream>>>(hfin, cbuf, out);
    }
}